// Round 15
// baseline (64.400 us; speedup 1.0000x reference)
//
#include <hip/hip_runtime.h>
#include <math.h>

#define NSM 4
#define NCELL 64

typedef float f32x2 __attribute__((ext_vector_type(2)));

#define TANH_SC 2.8853900817779268f   // 2*log2(e): tanh(x)=1-2/(exp2(SC*x)+1)

// ---------- helpers ----------

__device__ __forceinline__ f32x2 splat2(float s) { f32x2 v; v.x = s; v.y = s; return v; }

__device__ __forceinline__ f32x2 pkfma(f32x2 a, f32x2 b, f32x2 c) {
#if __has_builtin(__builtin_elementwise_fma)
    return __builtin_elementwise_fma(a, b, c);
#else
    f32x2 r; r.x = fmaf(a.x, b.x, c.x); r.y = fmaf(a.y, b.y, c.y); return r;
#endif
}

__device__ __forceinline__ float fast_exp2(float x) {
#if __has_builtin(__builtin_amdgcn_exp2f)
    return __builtin_amdgcn_exp2f(x);
#else
    return exp2f(x);
#endif
}

__device__ __forceinline__ void inv3x3(const float* __restrict__ C, float* inv) {
    float a=C[0],b=C[1],c=C[2],d=C[3],e=C[4],f=C[5],g=C[6],h=C[7],i=C[8];
    float A  =  (e*i - f*h);
    float B  = -(d*i - f*g);
    float Cc =  (d*h - e*g);
    float det = a*A + b*B + c*Cc;
    float rd = 1.0f/det;
    inv[0] = A*rd;        inv[1] = (c*h - b*i)*rd; inv[2] = (b*f - c*e)*rd;
    inv[3] = B*rd;        inv[4] = (a*i - c*g)*rd; inv[5] = (c*d - a*f)*rd;
    inv[6] = Cc*rd;       inv[7] = (b*g - a*h)*rd; inv[8] = (a*e - b*d)*rd;
}

// 3-point M3 weights + center index.
struct AxW { float wm, w0, wp; int n; };
__device__ __forceinline__ AxW axw(float u) {
    AxW r;
    float nf = rintf(u);
    float x  = u - nf;
    r.w0 = 0.75f - x*x;
    float tm = 0.5f - x;  r.wm = 0.5f*tm*tm;
    float tp = 0.5f + x;  r.wp = 0.5f*tp*tp;
    r.n = ((int)nf) & 3;
    return r;
}

// 4-wide periodic weights (rotated dense form).
__device__ __forceinline__ void axis_w4(float u, float* __restrict__ W) {
    AxW a = axw(u);
    #pragma unroll
    for (int j = 0; j < 4; j++) {
        float w = (a.n == j)         ? a.w0 : 0.0f;
        w       = (a.n == ((j+1)&3)) ? a.wm : w;
        w       = (a.n == ((j+3)&3)) ? a.wp : w;
        W[j] = w;
    }
}

// tanh(x) = 1 - 2/(exp2(SC*x)+1)
__device__ __forceinline__ float tanh1(float x) {
    float e = fast_exp2(x * TANH_SC);
    return fmaf(-2.0f, __builtin_amdgcn_rcpf(e + 1.0f), 1.0f);
}
__device__ __forceinline__ f32x2 tanh2v(f32x2 v) {
    float e0 = fast_exp2(v.x * TANH_SC);
    float e1 = fast_exp2(v.y * TANH_SC);
    f32x2 r;
    r.x = fmaf(-2.0f, __builtin_amdgcn_rcpf(e0 + 1.0f), 1.0f);
    r.y = fmaf(-2.0f, __builtin_amdgcn_rcpf(e1 + 1.0f), 1.0f);
    return r;
}

// ---------- kernel A: scatter, 8 particles/thread, R13 staged reduction ----------

__device__ __forceinline__ void scatter_one(float px, float py, float pz, float q,
                                            const float* __restrict__ ci,
                                            f32x2* __restrict__ macc) {
    float fx = px*ci[0] + py*ci[3] + pz*ci[6];
    float fy = px*ci[1] + py*ci[4] + pz*ci[7];
    float fz = px*ci[2] + py*ci[5] + pz*ci[8];
    float X[4], Y[4], Z[4];
    axis_w4(fx*(float)NSM, X);
    axis_w4(fy*(float)NSM, Y);
    axis_w4(fz*(float)NSM, Z);
    f32x2 z01; z01.x = Z[0]; z01.y = Z[1];
    f32x2 z23; z23.x = Z[2]; z23.y = Z[3];
    float qX[4];
    #pragma unroll
    for (int x = 0; x < 4; x++) qX[x] = q * X[x];
    #pragma unroll
    for (int x = 0; x < 4; x++) {
        #pragma unroll
        for (int y = 0; y < 4; y++) {
            f32x2 w2 = splat2(qX[x] * Y[y]);
            macc[x*8 + y*2    ] = pkfma(w2, z01, macc[x*8 + y*2    ]);
            macc[x*8 + y*2 + 1] = pkfma(w2, z23, macc[x*8 + y*2 + 1]);
        }
    }
}

__global__ __launch_bounds__(256) void scatter_kernel(
        const float* __restrict__ pos, const float* __restrict__ cell,
        const float* __restrict__ charges, float* __restrict__ partial, int N) {
    __shared__ f32x2 red[128][32];   // 32 KB
    __shared__ f32x2 red2[8][32];    // 2 KB
    float ci[9]; inv3x3(cell, ci);

    f32x2 macc[32];
    #pragma unroll
    for (int c = 0; c < 32; c++) macc[c] = splat2(0.0f);

    const float4* posv = (const float4*)pos;
    const float4* qv   = (const float4*)charges;
    long NB4    = ((long)N + 3) / 4;
    long stride = (long)gridDim.x * blockDim.x;

    // two float4-batches per thread: b and b+stride (fixed set, coalesced)
    #pragma unroll
    for (int pass = 0; pass < 2; pass++) {
        long b = (long)blockIdx.x * blockDim.x + threadIdx.x + pass * stride;
        if (b >= NB4) break;
        long i = b * 4;
        if (i + 3 < N) {
            float4 p0 = posv[3*b], p1 = posv[3*b+1], p2 = posv[3*b+2];
            float4 q4 = qv[b];
            scatter_one(p0.x, p0.y, p0.z, q4.x, ci, macc);
            scatter_one(p0.w, p1.x, p1.y, q4.y, ci, macc);
            scatter_one(p1.z, p1.w, p2.x, q4.z, ci, macc);
            scatter_one(p2.y, p2.z, p2.w, q4.w, ci, macc);
        } else {
            for (long k = i; k < N; k++)
                scatter_one(pos[3*k], pos[3*k+1], pos[3*k+2], charges[k], ci, macc);
        }
    }

    // wave pre-reduce: lane l += lane l^32 -> lower 32 lanes hold pair sums
    #pragma unroll
    for (int c = 0; c < 32; c++) {
        macc[c].x += __shfl_xor(macc[c].x, 32);
        macc[c].y += __shfl_xor(macc[c].y, 32);
    }
    int t = threadIdx.x;
    int row = (t >> 6) * 32 + (t & 31);
    if ((t & 32) == 0) {
        int sw = t & 31;
        #pragma unroll
        for (int c = 0; c < 32; c++) red[row][c ^ sw] = macc[c];
    }
    __syncthreads();
    {
        int p = t & 31, g = t >> 5;
        f32x2 sum = splat2(0.0f);
        #pragma unroll
        for (int i2 = 0; i2 < 16; i2++) {
            int r = g*16 + i2;
            sum += red[r][p ^ (r & 31)];
        }
        red2[g][p] = sum;
    }
    __syncthreads();
    if (t < NCELL) {
        const float* r2 = (const float*)&red2[0][0];
        int pair = t >> 1, comp = t & 1;
        float s = 0.0f;
        #pragma unroll
        for (int gg = 0; gg < 8; gg++) s += r2[(gg*32 + pair)*2 + comp];
        partial[(long)blockIdx.x * NCELL + t] = s;   // plain store, no atomic
    }
}

// ---------- kernel B: merged fixed-order reduce + Green's fn + circular conv ----------
// One block, 1024 threads. Threads 64..127 compute gr[] concurrently with the
// row-reduce. mesh'[r] = sum G[(r-r')&3] mesh[r']; no 1/64 norm factor.

__global__ __launch_bounds__(1024) void reduce_filter_kernel(
        const float* __restrict__ partial, int nb,
        const float* __restrict__ cell, const float* __restrict__ sigma2p,
        float* __restrict__ mesh_out) {
    __shared__ float acc[16][64];
    __shared__ float mm[64];
    __shared__ float gr[64];
    int t = threadIdx.x;
    int c = t & 63, g = t >> 6;          // 16 row-phases

    // fixed-order sum: phase g handles rows {g, g+16, g+32, ...}
    float s = 0.0f;
    for (int r = g; r < nb; r += 16)
        s += partial[(long)r * NCELL + c];
    acc[g][c] = s;

    // Green's function on threads 64..127 (concurrent with the reduce wave)
    if (t >= 64 && t < 128) {
        int tt = t - 64;
        float ci[9]; inv3x3(cell, ci);
        float s2 = sigma2p[0];
        const float twopi = 6.2831853071795864769f;
        float G0x = twopi*ci[0], G0y = twopi*ci[3], G0z = twopi*ci[6];
        float G1x = twopi*ci[1], G1y = twopi*ci[4], G1z = twopi*ci[7];
        float G2x = twopi*ci[2], G2y = twopi*ci[5], G2z = twopi*ci[8];
        int dx = tt >> 4, dy = (tt >> 2) & 3, dz = tt & 3;
        float accg = 0.0f;
        for (int a = 0; a < 4; a++) {
            float fa = (a < 2) ? (float)a : (float)(a - 4);
            for (int b = 0; b < 4; b++) {
                float fb = (b < 2) ? (float)b : (float)(b - 4);
                for (int cc = 0; cc < 4; cc++) {
                    if ((a | b | cc) == 0) continue;
                    float fc = (cc < 2) ? (float)cc : (float)(cc - 4);
                    float kx = fa*G0x + fb*G1x + fc*G2x;
                    float ky = fa*G0y + fb*G1y + fc*G2y;
                    float kz = fa*G0z + fb*G1z + fc*G2z;
                    float k2 = kx*kx + ky*ky + kz*kz;
                    float K  = expf(-k2 * s2 * 0.5f) / k2;
                    int ph = (a*dx + b*dy + cc*dz) & 3;
                    float cs = (ph == 0) ? 1.0f : ((ph == 2) ? -1.0f : 0.0f);
                    accg += K * cs;
                }
            }
        }
        gr[tt] = accg;
    }
    __syncthreads();
    if (t < 64) {
        float v = 0.0f;
        #pragma unroll
        for (int gg = 0; gg < 16; gg++) v += acc[gg][t];
        mm[t] = v;
    }
    __syncthreads();
    if (t < 64) {
        int dx = t >> 4, dy = (t >> 2) & 3, dz = t & 3;
        float o = 0.0f;
        for (int s2i = 0; s2i < 64; s2i++) {
            int sx = s2i >> 4, sy = (s2i >> 2) & 3, sz = s2i & 3;
            int d = ((dx - sx) & 3)*16 + ((dy - sy) & 3)*4 + ((dz - sz) & 3);
            o += gr[d] * mm[s2i];
        }
        mesh_out[t] = o;
    }
}

// ---------- kernel C: gather (dense, mesh via uniform GLOBAL scalar loads) ----------

__device__ __forceinline__ float pot_one(float px, float py, float pz,
                                         const float* __restrict__ ci,
                                         const float* __restrict__ mf) {
    float fx = px*ci[0] + py*ci[3] + pz*ci[6];
    float fy = px*ci[1] + py*ci[4] + pz*ci[7];
    float fz = px*ci[2] + py*ci[5] + pz*ci[8];
    float X[4], Y[4], Z[4];
    axis_w4(fx*(float)NSM, X);
    axis_w4(fy*(float)NSM, Y);
    axis_w4(fz*(float)NSM, Z);
    f32x2 a01 = splat2(0.0f), a23 = splat2(0.0f);
    #pragma unroll
    for (int x = 0; x < 4; x++) {
        #pragma unroll
        for (int y = 0; y < 4; y++) {
            f32x2 w2 = splat2(X[x] * Y[y]);
            f32x2 m01, m23;
            m01.x = mf[x*16 + y*4 + 0]; m01.y = mf[x*16 + y*4 + 1];
            m23.x = mf[x*16 + y*4 + 2]; m23.y = mf[x*16 + y*4 + 3];
            a01 = pkfma(w2, m01, a01);
            a23 = pkfma(w2, m23, a23);
        }
    }
    return a01.x*Z[0] + a01.y*Z[1] + a23.x*Z[2] + a23.y*Z[3];
}

__global__ __launch_bounds__(256, 4) void gather_mlp_kernel(
        const float* __restrict__ pos, const float* __restrict__ cell,
        const float* __restrict__ charges,
        const float* __restrict__ W1, const float* __restrict__ b1,
        const float* __restrict__ W2, const float* __restrict__ b2,
        const float* __restrict__ W3, const float* __restrict__ b3,
        const float* __restrict__ meshf, float* __restrict__ bsum, int N) {
    __shared__ float wavesum[4];
    int t = threadIdx.x;
    float ci[9]; inv3x3(cell, ci);

    long t4 = (long)blockIdx.x * blockDim.x + threadIdx.x;
    long i0 = t4 * 4;
    float ysum = 0.0f;

    if (i0 + 3 < N) {
        const float4* posv = (const float4*)pos;
        float4 p0 = posv[3*t4], p1 = posv[3*t4+1], p2 = posv[3*t4+2];
        float4 q4 = ((const float4*)charges)[t4];

        float pt0 = pot_one(p0.x, p0.y, p0.z, ci, meshf);
        float pt1 = pot_one(p0.w, p1.x, p1.y, ci, meshf);
        float pt2 = pot_one(p1.z, p1.w, p2.x, ci, meshf);
        float pt3 = pot_one(p2.y, p2.z, p2.w, ci, meshf);

        f32x2 q01; q01.x = q4.x; q01.y = q4.y;
        f32x2 q23; q23.x = q4.z; q23.y = q4.w;
        f32x2 pA;  pA.x = pt0;  pA.y = pt1;
        f32x2 pB;  pB.x = pt2;  pB.y = pt3;

        // weights read raw from global (uniform -> s_load operands, no VGPR cost)
        f32x2 h1a[10], h1b[10];
        #pragma unroll
        for (int j = 0; j < 10; j++) {
            f32x2 ta = pkfma(pA, splat2(W1[10 + j]), splat2(b1[j]));
            ta = pkfma(q01, splat2(W1[j]), ta);
            h1a[j] = tanh2v(ta);
            f32x2 tb = pkfma(pB, splat2(W1[10 + j]), splat2(b1[j]));
            tb = pkfma(q23, splat2(W1[j]), tb);
            h1b[j] = tanh2v(tb);
        }
        f32x2 h2a[10], h2b[10];
        #pragma unroll
        for (int j = 0; j < 10; j++) {
            f32x2 aa = splat2(b2[j]), ab = splat2(b2[j]);
            #pragma unroll
            for (int i = 0; i < 10; i++) {
                f32x2 w = splat2(W2[10*i + j]);
                aa = pkfma(h1a[i], w, aa);
                ab = pkfma(h1b[i], w, ab);
            }
            h2a[j] = tanh2v(aa);
            h2b[j] = tanh2v(ab);
        }
        f32x2 ya = splat2(b3[0]), yb = splat2(b3[0]);
        #pragma unroll
        for (int j = 0; j < 10; j++) {
            f32x2 w = splat2(W3[j]);
            ya = pkfma(h2a[j], w, ya);
            yb = pkfma(h2b[j], w, yb);
        }
        ysum = ya.x + ya.y + yb.x + yb.y;
    } else if (i0 < N) {
        for (long k = i0; k < N; k++) {
            float pt = pot_one(pos[3*k], pos[3*k+1], pos[3*k+2], ci, meshf);
            float q  = charges[k];
            float h1[10], h2[10];
            #pragma unroll
            for (int j = 0; j < 10; j++)
                h1[j] = tanh1(fmaf(q, W1[j], fmaf(pt, W1[10 + j], b1[j])));
            #pragma unroll
            for (int j = 0; j < 10; j++) {
                float a2 = b2[j];
                #pragma unroll
                for (int i = 0; i < 10; i++) a2 = fmaf(h1[i], W2[10*i + j], a2);
                h2[j] = tanh1(a2);
            }
            float y = b3[0];
            #pragma unroll
            for (int j = 0; j < 10; j++) y = fmaf(h2[j], W3[j], y);
            ysum += y;
        }
    }

    ysum += __shfl_down(ysum, 32);
    ysum += __shfl_down(ysum, 16);
    ysum += __shfl_down(ysum, 8);
    ysum += __shfl_down(ysum, 4);
    ysum += __shfl_down(ysum, 2);
    ysum += __shfl_down(ysum, 1);
    int wid  = t >> 6;
    int lane = t & 63;
    if (lane == 0) wavesum[wid] = ysum;
    __syncthreads();
    if (t == 0)
        bsum[blockIdx.x] = wavesum[0] + wavesum[1] + wavesum[2] + wavesum[3];
}

// ---------- kernel D: deterministic final sum ----------

__global__ __launch_bounds__(256) void final_sum_kernel(
        const float* __restrict__ bsum, int nb, float* __restrict__ out) {
    __shared__ float wavesum[4];
    float s = 0.0f;
    for (int i = threadIdx.x; i < nb; i += 256) s += bsum[i];
    s += __shfl_down(s, 32);
    s += __shfl_down(s, 16);
    s += __shfl_down(s, 8);
    s += __shfl_down(s, 4);
    s += __shfl_down(s, 2);
    s += __shfl_down(s, 1);
    int wid  = threadIdx.x >> 6;
    int lane = threadIdx.x & 63;
    if (lane == 0) wavesum[wid] = s;
    __syncthreads();
    if (threadIdx.x == 0)
        out[0] = wavesum[0] + wavesum[1] + wavesum[2] + wavesum[3];
}

// ---------- launch ----------

extern "C" void kernel_launch(void* const* d_in, const int* in_sizes, int n_in,
                              void* d_out, int out_size, void* d_ws, size_t ws_size,
                              hipStream_t stream) {
    const float* pos     = (const float*)d_in[0];
    const float* cell    = (const float*)d_in[1];
    const float* charges = (const float*)d_in[2];
    const float* sigma2  = (const float*)d_in[3];
    const float* W1 = (const float*)d_in[4];
    const float* b1 = (const float*)d_in[5];
    const float* W2 = (const float*)d_in[6];
    const float* b2 = (const float*)d_in[7];
    const float* W3 = (const float*)d_in[8];
    const float* b3 = (const float*)d_in[9];
    int N = in_sizes[2];                         // charges (N,1)

    int sc_blocks = (int)(((long)N + 2047) / 2048);   // 8 particles/thread
    int ga_blocks = (int)(((long)N + 1023) / 1024);   // 4 particles/thread

    // ws layout: partial[sc_blocks*64] | meshf[64] | bsum[ga_blocks]
    float* partial = (float*)d_ws;
    float* meshf   = partial + (long)sc_blocks * NCELL;
    float* bsum    = meshf + NCELL;

    scatter_kernel<<<sc_blocks, 256, 0, stream>>>(pos, cell, charges, partial, N);
    reduce_filter_kernel<<<1, 1024, 0, stream>>>(partial, sc_blocks,
                                                 cell, sigma2, meshf);
    gather_mlp_kernel<<<ga_blocks, 256, 0, stream>>>(pos, cell, charges,
                                                     W1, b1, W2, b2, W3, b3,
                                                     meshf, bsum, N);
    final_sum_kernel<<<1, 256, 0, stream>>>(bsum, ga_blocks, (float*)d_out);
}

// Round 16
// 53.109 us; speedup vs baseline: 1.2126x; 1.2126x over previous
//
#include <hip/hip_runtime.h>
#include <math.h>

#define NSM 4
#define NCELL 64
#define R1_BLOCKS 64

typedef float f32x2 __attribute__((ext_vector_type(2)));

#define TANH_SC 2.8853900817779268f   // 2*log2(e): tanh(x)=1-2/(exp2(SC*x)+1)

// ---------- helpers ----------

__device__ __forceinline__ f32x2 splat2(float s) { f32x2 v; v.x = s; v.y = s; return v; }

__device__ __forceinline__ f32x2 pkfma(f32x2 a, f32x2 b, f32x2 c) {
#if __has_builtin(__builtin_elementwise_fma)
    return __builtin_elementwise_fma(a, b, c);
#else
    f32x2 r; r.x = fmaf(a.x, b.x, c.x); r.y = fmaf(a.y, b.y, c.y); return r;
#endif
}

__device__ __forceinline__ float fast_exp2(float x) {
#if __has_builtin(__builtin_amdgcn_exp2f)
    return __builtin_amdgcn_exp2f(x);
#else
    return exp2f(x);
#endif
}

__device__ __forceinline__ void inv3x3(const float* __restrict__ C, float* inv) {
    float a=C[0],b=C[1],c=C[2],d=C[3],e=C[4],f=C[5],g=C[6],h=C[7],i=C[8];
    float A  =  (e*i - f*h);
    float B  = -(d*i - f*g);
    float Cc =  (d*h - e*g);
    float det = a*A + b*B + c*Cc;
    float rd = 1.0f/det;
    inv[0] = A*rd;        inv[1] = (c*h - b*i)*rd; inv[2] = (b*f - c*e)*rd;
    inv[3] = B*rd;        inv[4] = (a*i - c*g)*rd; inv[5] = (c*d - a*f)*rd;
    inv[6] = Cc*rd;       inv[7] = (b*g - a*h)*rd; inv[8] = (a*e - b*d)*rd;
}

// 3-point M3 weights + center index.
struct AxW { float wm, w0, wp; int n; };
__device__ __forceinline__ AxW axw(float u) {
    AxW r;
    float nf = rintf(u);
    float x  = u - nf;
    r.w0 = 0.75f - x*x;
    float tm = 0.5f - x;  r.wm = 0.5f*tm*tm;
    float tp = 0.5f + x;  r.wp = 0.5f*tp*tp;
    r.n = ((int)nf) & 3;
    return r;
}

// 4-wide periodic weights (rotated dense form).
__device__ __forceinline__ void axis_w4(float u, float* __restrict__ W) {
    AxW a = axw(u);
    #pragma unroll
    for (int j = 0; j < 4; j++) {
        float w = (a.n == j)         ? a.w0 : 0.0f;
        w       = (a.n == ((j+1)&3)) ? a.wm : w;
        w       = (a.n == ((j+3)&3)) ? a.wp : w;
        W[j] = w;
    }
}

// tanh(x) = 1 - 2/(exp2(SC*x)+1)
__device__ __forceinline__ float tanh1(float x) {
    float e = fast_exp2(x * TANH_SC);
    return fmaf(-2.0f, __builtin_amdgcn_rcpf(e + 1.0f), 1.0f);
}
__device__ __forceinline__ f32x2 tanh2v(f32x2 v) {
    float e0 = fast_exp2(v.x * TANH_SC);
    float e1 = fast_exp2(v.y * TANH_SC);
    f32x2 r;
    r.x = fmaf(-2.0f, __builtin_amdgcn_rcpf(e0 + 1.0f), 1.0f);
    r.y = fmaf(-2.0f, __builtin_amdgcn_rcpf(e1 + 1.0f), 1.0f);
    return r;
}

// ---------- kernel A: scatter, 8 particles/thread, R13 staged reduction ----------

__device__ __forceinline__ void scatter_one(float px, float py, float pz, float q,
                                            const float* __restrict__ ci,
                                            f32x2* __restrict__ macc) {
    float fx = px*ci[0] + py*ci[3] + pz*ci[6];
    float fy = px*ci[1] + py*ci[4] + pz*ci[7];
    float fz = px*ci[2] + py*ci[5] + pz*ci[8];
    float X[4], Y[4], Z[4];
    axis_w4(fx*(float)NSM, X);
    axis_w4(fy*(float)NSM, Y);
    axis_w4(fz*(float)NSM, Z);
    f32x2 z01; z01.x = Z[0]; z01.y = Z[1];
    f32x2 z23; z23.x = Z[2]; z23.y = Z[3];
    float qX[4];
    #pragma unroll
    for (int x = 0; x < 4; x++) qX[x] = q * X[x];
    #pragma unroll
    for (int x = 0; x < 4; x++) {
        #pragma unroll
        for (int y = 0; y < 4; y++) {
            f32x2 w2 = splat2(qX[x] * Y[y]);
            macc[x*8 + y*2    ] = pkfma(w2, z01, macc[x*8 + y*2    ]);
            macc[x*8 + y*2 + 1] = pkfma(w2, z23, macc[x*8 + y*2 + 1]);
        }
    }
}

__global__ __launch_bounds__(256) void scatter_kernel(
        const float* __restrict__ pos, const float* __restrict__ cell,
        const float* __restrict__ charges, float* __restrict__ partial, int N) {
    __shared__ f32x2 red[128][32];   // 32 KB
    __shared__ f32x2 red2[8][32];    // 2 KB
    float ci[9]; inv3x3(cell, ci);

    f32x2 macc[32];
    #pragma unroll
    for (int c = 0; c < 32; c++) macc[c] = splat2(0.0f);

    const float4* posv = (const float4*)pos;
    const float4* qv   = (const float4*)charges;
    long NB4    = ((long)N + 3) / 4;
    long stride = (long)gridDim.x * blockDim.x;

    // two float4-batches per thread: b and b+stride (fixed set, coalesced)
    #pragma unroll
    for (int pass = 0; pass < 2; pass++) {
        long b = (long)blockIdx.x * blockDim.x + threadIdx.x + pass * stride;
        if (b >= NB4) break;
        long i = b * 4;
        if (i + 3 < N) {
            float4 p0 = posv[3*b], p1 = posv[3*b+1], p2 = posv[3*b+2];
            float4 q4 = qv[b];
            scatter_one(p0.x, p0.y, p0.z, q4.x, ci, macc);
            scatter_one(p0.w, p1.x, p1.y, q4.y, ci, macc);
            scatter_one(p1.z, p1.w, p2.x, q4.z, ci, macc);
            scatter_one(p2.y, p2.z, p2.w, q4.w, ci, macc);
        } else {
            for (long k = i; k < N; k++)
                scatter_one(pos[3*k], pos[3*k+1], pos[3*k+2], charges[k], ci, macc);
        }
    }

    // wave pre-reduce: lane l += lane l^32 -> lower 32 lanes hold pair sums
    #pragma unroll
    for (int c = 0; c < 32; c++) {
        macc[c].x += __shfl_xor(macc[c].x, 32);
        macc[c].y += __shfl_xor(macc[c].y, 32);
    }
    int t = threadIdx.x;
    int row = (t >> 6) * 32 + (t & 31);
    if ((t & 32) == 0) {
        int sw = t & 31;
        #pragma unroll
        for (int c = 0; c < 32; c++) red[row][c ^ sw] = macc[c];
    }
    __syncthreads();
    {
        int p = t & 31, g = t >> 5;
        f32x2 sum = splat2(0.0f);
        #pragma unroll
        for (int i2 = 0; i2 < 16; i2++) {
            int r = g*16 + i2;
            sum += red[r][p ^ (r & 31)];
        }
        red2[g][p] = sum;
    }
    __syncthreads();
    if (t < NCELL) {
        const float* r2 = (const float*)&red2[0][0];
        int pair = t >> 1, comp = t & 1;
        float s = 0.0f;
        #pragma unroll
        for (int gg = 0; gg < 8; gg++) s += r2[(gg*32 + pair)*2 + comp];
        partial[(long)blockIdx.x * NCELL + t] = s;   // plain store, no atomic
    }
}

// ---------- kernel B1: fixed-order tree reduce: nb rows -> 64 rows ----------

__global__ __launch_bounds__(256) void reduce_stage1_kernel(
        const float* __restrict__ partial, int nb, float* __restrict__ partial2) {
    __shared__ float acc[4][64];
    int t = threadIdx.x;
    int c = t & 63, g = t >> 6;
    float s = 0.0f;
    for (int r = blockIdx.x + 64*g; r < nb; r += 256)
        s += partial[(long)r * NCELL + c];
    acc[g][c] = s;
    __syncthreads();
    if (t < 64) {
        float v = ((acc[0][t] + acc[1][t]) + acc[2][t]) + acc[3][t];
        partial2[(long)blockIdx.x * NCELL + t] = v;
    }
}

// ---------- kernel B2: final 64-row reduce + k-space filter ----------
// mesh'[r] = sum_{r'} G[(r-r') mod 4] mesh[r'];  no 1/64 (backward rfft, forward irfft)

__global__ __launch_bounds__(256) void reduce_filter_kernel(
        const float* __restrict__ partial2,
        const float* __restrict__ cell, const float* __restrict__ sigma2p,
        float* __restrict__ mesh_out) {
    __shared__ float4 redA[16][16];
    __shared__ float mm[64];
    __shared__ float gr[64];
    int t = threadIdx.x;

    int c4 = t & 15, g = t >> 4;
    float4 v = make_float4(0.f, 0.f, 0.f, 0.f);
    const float4* p4 = (const float4*)partial2;
    for (int b = g; b < R1_BLOCKS; b += 16) {
        float4 x = p4[b*16 + c4];
        v.x += x.x; v.y += x.y; v.z += x.z; v.w += x.w;
    }
    redA[g][c4] = v;
    __syncthreads();
    if (t < 16) {
        float4 tot = make_float4(0.f, 0.f, 0.f, 0.f);
        #pragma unroll
        for (int gg = 0; gg < 16; gg++) {
            float4 x = redA[gg][t];
            tot.x += x.x; tot.y += x.y; tot.z += x.z; tot.w += x.w;
        }
        ((float4*)mm)[t] = tot;
    }
    __syncthreads();

    if (t < 64) {
        float ci[9]; inv3x3(cell, ci);
        float s2 = sigma2p[0];
        const float twopi = 6.2831853071795864769f;
        float G0x = twopi*ci[0], G0y = twopi*ci[3], G0z = twopi*ci[6];
        float G1x = twopi*ci[1], G1y = twopi*ci[4], G1z = twopi*ci[7];
        float G2x = twopi*ci[2], G2y = twopi*ci[5], G2z = twopi*ci[8];
        int dx = t >> 4, dy = (t >> 2) & 3, dz = t & 3;
        float acc = 0.0f;
        for (int a = 0; a < 4; a++) {
            float fa = (a < 2) ? (float)a : (float)(a - 4);
            for (int b = 0; b < 4; b++) {
                float fb = (b < 2) ? (float)b : (float)(b - 4);
                for (int c = 0; c < 4; c++) {
                    if ((a | b | c) == 0) continue;
                    float fc = (c < 2) ? (float)c : (float)(c - 4);
                    float kx = fa*G0x + fb*G1x + fc*G2x;
                    float ky = fa*G0y + fb*G1y + fc*G2y;
                    float kz = fa*G0z + fb*G1z + fc*G2z;
                    float k2 = kx*kx + ky*ky + kz*kz;
                    float K  = expf(-k2 * s2 * 0.5f) / k2;
                    int ph = (a*dx + b*dy + c*dz) & 3;
                    float cs = (ph == 0) ? 1.0f : ((ph == 2) ? -1.0f : 0.0f);
                    acc += K * cs;
                }
            }
        }
        gr[t] = acc;
    }
    __syncthreads();
    if (t < 64) {
        int dx = t >> 4, dy = (t >> 2) & 3, dz = t & 3;
        float o = 0.0f;
        for (int s = 0; s < 64; s++) {
            int sx = s >> 4, sy = (s >> 2) & 3, sz = s & 3;
            int d = ((dx - sx) & 3)*16 + ((dy - sy) & 3)*4 + ((dz - sz) & 3);
            o += gr[d] * mm[s];
        }
        mesh_out[t] = o;
    }
}

// ---------- kernel C: gather (dense, mesh via uniform GLOBAL scalar loads) ----------

__device__ __forceinline__ float pot_one(float px, float py, float pz,
                                         const float* __restrict__ ci,
                                         const float* __restrict__ mf) {
    float fx = px*ci[0] + py*ci[3] + pz*ci[6];
    float fy = px*ci[1] + py*ci[4] + pz*ci[7];
    float fz = px*ci[2] + py*ci[5] + pz*ci[8];
    float X[4], Y[4], Z[4];
    axis_w4(fx*(float)NSM, X);
    axis_w4(fy*(float)NSM, Y);
    axis_w4(fz*(float)NSM, Z);
    f32x2 a01 = splat2(0.0f), a23 = splat2(0.0f);
    #pragma unroll
    for (int x = 0; x < 4; x++) {
        #pragma unroll
        for (int y = 0; y < 4; y++) {
            f32x2 w2 = splat2(X[x] * Y[y]);
            f32x2 m01, m23;
            m01.x = mf[x*16 + y*4 + 0]; m01.y = mf[x*16 + y*4 + 1];
            m23.x = mf[x*16 + y*4 + 2]; m23.y = mf[x*16 + y*4 + 3];
            a01 = pkfma(w2, m01, a01);
            a23 = pkfma(w2, m23, a23);
        }
    }
    return a01.x*Z[0] + a01.y*Z[1] + a23.x*Z[2] + a23.y*Z[3];
}

__global__ __launch_bounds__(256, 4) void gather_mlp_kernel(
        const float* __restrict__ pos, const float* __restrict__ cell,
        const float* __restrict__ charges,
        const float* __restrict__ W1, const float* __restrict__ b1,
        const float* __restrict__ W2, const float* __restrict__ b2,
        const float* __restrict__ W3, const float* __restrict__ b3,
        const float* __restrict__ meshf, float* __restrict__ bsum, int N) {
    __shared__ float wavesum[4];
    int t = threadIdx.x;
    float ci[9]; inv3x3(cell, ci);

    long t4 = (long)blockIdx.x * blockDim.x + threadIdx.x;
    long i0 = t4 * 4;
    float ysum = 0.0f;

    if (i0 + 3 < N) {
        const float4* posv = (const float4*)pos;
        float4 p0 = posv[3*t4], p1 = posv[3*t4+1], p2 = posv[3*t4+2];
        float4 q4 = ((const float4*)charges)[t4];

        float pt0 = pot_one(p0.x, p0.y, p0.z, ci, meshf);
        float pt1 = pot_one(p0.w, p1.x, p1.y, ci, meshf);
        float pt2 = pot_one(p1.z, p1.w, p2.x, ci, meshf);
        float pt3 = pot_one(p2.y, p2.z, p2.w, ci, meshf);

        f32x2 q01; q01.x = q4.x; q01.y = q4.y;
        f32x2 q23; q23.x = q4.z; q23.y = q4.w;
        f32x2 pA;  pA.x = pt0;  pA.y = pt1;
        f32x2 pB;  pB.x = pt2;  pB.y = pt3;

        // weights read raw from global (uniform -> s_load operands, no VGPR cost)
        f32x2 h1a[10], h1b[10];
        #pragma unroll
        for (int j = 0; j < 10; j++) {
            f32x2 ta = pkfma(pA, splat2(W1[10 + j]), splat2(b1[j]));
            ta = pkfma(q01, splat2(W1[j]), ta);
            h1a[j] = tanh2v(ta);
            f32x2 tb = pkfma(pB, splat2(W1[10 + j]), splat2(b1[j]));
            tb = pkfma(q23, splat2(W1[j]), tb);
            h1b[j] = tanh2v(tb);
        }
        f32x2 h2a[10], h2b[10];
        #pragma unroll
        for (int j = 0; j < 10; j++) {
            f32x2 aa = splat2(b2[j]), ab = splat2(b2[j]);
            #pragma unroll
            for (int i = 0; i < 10; i++) {
                f32x2 w = splat2(W2[10*i + j]);
                aa = pkfma(h1a[i], w, aa);
                ab = pkfma(h1b[i], w, ab);
            }
            h2a[j] = tanh2v(aa);
            h2b[j] = tanh2v(ab);
        }
        f32x2 ya = splat2(b3[0]), yb = splat2(b3[0]);
        #pragma unroll
        for (int j = 0; j < 10; j++) {
            f32x2 w = splat2(W3[j]);
            ya = pkfma(h2a[j], w, ya);
            yb = pkfma(h2b[j], w, yb);
        }
        ysum = ya.x + ya.y + yb.x + yb.y;
    } else if (i0 < N) {
        for (long k = i0; k < N; k++) {
            float pt = pot_one(pos[3*k], pos[3*k+1], pos[3*k+2], ci, meshf);
            float q  = charges[k];
            float h1[10], h2[10];
            #pragma unroll
            for (int j = 0; j < 10; j++)
                h1[j] = tanh1(fmaf(q, W1[j], fmaf(pt, W1[10 + j], b1[j])));
            #pragma unroll
            for (int j = 0; j < 10; j++) {
                float a2 = b2[j];
                #pragma unroll
                for (int i = 0; i < 10; i++) a2 = fmaf(h1[i], W2[10*i + j], a2);
                h2[j] = tanh1(a2);
            }
            float y = b3[0];
            #pragma unroll
            for (int j = 0; j < 10; j++) y = fmaf(h2[j], W3[j], y);
            ysum += y;
        }
    }

    ysum += __shfl_down(ysum, 32);
    ysum += __shfl_down(ysum, 16);
    ysum += __shfl_down(ysum, 8);
    ysum += __shfl_down(ysum, 4);
    ysum += __shfl_down(ysum, 2);
    ysum += __shfl_down(ysum, 1);
    int wid  = t >> 6;
    int lane = t & 63;
    if (lane == 0) wavesum[wid] = ysum;
    __syncthreads();
    if (t == 0)
        bsum[blockIdx.x] = wavesum[0] + wavesum[1] + wavesum[2] + wavesum[3];
}

// ---------- kernel D: deterministic final sum ----------

__global__ __launch_bounds__(256) void final_sum_kernel(
        const float* __restrict__ bsum, int nb, float* __restrict__ out) {
    __shared__ float wavesum[4];
    float s = 0.0f;
    for (int i = threadIdx.x; i < nb; i += 256) s += bsum[i];
    s += __shfl_down(s, 32);
    s += __shfl_down(s, 16);
    s += __shfl_down(s, 8);
    s += __shfl_down(s, 4);
    s += __shfl_down(s, 2);
    s += __shfl_down(s, 1);
    int wid  = threadIdx.x >> 6;
    int lane = threadIdx.x & 63;
    if (lane == 0) wavesum[wid] = s;
    __syncthreads();
    if (threadIdx.x == 0)
        out[0] = wavesum[0] + wavesum[1] + wavesum[2] + wavesum[3];
}

// ---------- launch ----------

extern "C" void kernel_launch(void* const* d_in, const int* in_sizes, int n_in,
                              void* d_out, int out_size, void* d_ws, size_t ws_size,
                              hipStream_t stream) {
    const float* pos     = (const float*)d_in[0];
    const float* cell    = (const float*)d_in[1];
    const float* charges = (const float*)d_in[2];
    const float* sigma2  = (const float*)d_in[3];
    const float* W1 = (const float*)d_in[4];
    const float* b1 = (const float*)d_in[5];
    const float* W2 = (const float*)d_in[6];
    const float* b2 = (const float*)d_in[7];
    const float* W3 = (const float*)d_in[8];
    const float* b3 = (const float*)d_in[9];
    int N = in_sizes[2];                         // charges (N,1)

    int sc_blocks = (int)(((long)N + 2047) / 2048);   // 8 particles/thread
    int ga_blocks = (int)(((long)N + 1023) / 1024);   // 4 particles/thread

    // ws layout: partial[sc_blocks*64] | partial2[64*64] | meshf[64] | bsum[ga_blocks]
    float* partial  = (float*)d_ws;
    float* partial2 = partial + (long)sc_blocks * NCELL;
    float* meshf    = partial2 + (long)R1_BLOCKS * NCELL;
    float* bsum     = meshf + NCELL;

    scatter_kernel<<<sc_blocks, 256, 0, stream>>>(pos, cell, charges, partial, N);
    reduce_stage1_kernel<<<R1_BLOCKS, 256, 0, stream>>>(partial, sc_blocks, partial2);
    reduce_filter_kernel<<<1, 256, 0, stream>>>(partial2, cell, sigma2, meshf);
    gather_mlp_kernel<<<ga_blocks, 256, 0, stream>>>(pos, cell, charges,
                                                     W1, b1, W2, b2, W3, b3,
                                                     meshf, bsum, N);
    final_sum_kernel<<<1, 256, 0, stream>>>(bsum, ga_blocks, (float*)d_out);
}

// Round 17
// 52.513 us; speedup vs baseline: 1.2264x; 1.0114x over previous
//
#include <hip/hip_runtime.h>
#include <math.h>

#define NSM 4
#define NCELL 64
#define R1_BLOCKS 64

typedef float f32x2 __attribute__((ext_vector_type(2)));

#define TANH_SC 2.8853900817779268f   // 2*log2(e): tanh(x)=1-2/(exp2(SC*x)+1)

// ---------- helpers ----------

__device__ __forceinline__ f32x2 splat2(float s) { f32x2 v; v.x = s; v.y = s; return v; }

__device__ __forceinline__ f32x2 pkfma(f32x2 a, f32x2 b, f32x2 c) {
#if __has_builtin(__builtin_elementwise_fma)
    return __builtin_elementwise_fma(a, b, c);
#else
    f32x2 r; r.x = fmaf(a.x, b.x, c.x); r.y = fmaf(a.y, b.y, c.y); return r;
#endif
}

__device__ __forceinline__ float fast_exp2(float x) {
#if __has_builtin(__builtin_amdgcn_exp2f)
    return __builtin_amdgcn_exp2f(x);
#else
    return exp2f(x);
#endif
}

__device__ __forceinline__ void inv3x3(const float* __restrict__ C, float* inv) {
    float a=C[0],b=C[1],c=C[2],d=C[3],e=C[4],f=C[5],g=C[6],h=C[7],i=C[8];
    float A  =  (e*i - f*h);
    float B  = -(d*i - f*g);
    float Cc =  (d*h - e*g);
    float det = a*A + b*B + c*Cc;
    float rd = 1.0f/det;
    inv[0] = A*rd;        inv[1] = (c*h - b*i)*rd; inv[2] = (b*f - c*e)*rd;
    inv[3] = B*rd;        inv[4] = (a*i - c*g)*rd; inv[5] = (c*d - a*f)*rd;
    inv[6] = Cc*rd;       inv[7] = (b*g - a*h)*rd; inv[8] = (a*e - b*d)*rd;
}

// 3-point M3 weights + center index.
struct AxW { float wm, w0, wp; int n; };
__device__ __forceinline__ AxW axw(float u) {
    AxW r;
    float nf = rintf(u);
    float x  = u - nf;
    r.w0 = 0.75f - x*x;
    float tm = 0.5f - x;  r.wm = 0.5f*tm*tm;
    float tp = 0.5f + x;  r.wp = 0.5f*tp*tp;
    r.n = ((int)nf) & 3;
    return r;
}

// 4-wide periodic weights (rotated dense form).
__device__ __forceinline__ void axis_w4(float u, float* __restrict__ W) {
    AxW a = axw(u);
    #pragma unroll
    for (int j = 0; j < 4; j++) {
        float w = (a.n == j)         ? a.w0 : 0.0f;
        w       = (a.n == ((j+1)&3)) ? a.wm : w;
        w       = (a.n == ((j+3)&3)) ? a.wp : w;
        W[j] = w;
    }
}

// tanh(x) = 1 - 2/(exp2(SC*x)+1)
__device__ __forceinline__ float tanh1(float x) {
    float e = fast_exp2(x * TANH_SC);
    return fmaf(-2.0f, __builtin_amdgcn_rcpf(e + 1.0f), 1.0f);
}
__device__ __forceinline__ f32x2 tanh2v(f32x2 v) {
    float e0 = fast_exp2(v.x * TANH_SC);
    float e1 = fast_exp2(v.y * TANH_SC);
    f32x2 r;
    r.x = fmaf(-2.0f, __builtin_amdgcn_rcpf(e0 + 1.0f), 1.0f);
    r.y = fmaf(-2.0f, __builtin_amdgcn_rcpf(e1 + 1.0f), 1.0f);
    return r;
}

// ---------- kernel A: scatter, 8 particles/thread, R13 staged reduction ----------

__device__ __forceinline__ void scatter_one(float px, float py, float pz, float q,
                                            const float* __restrict__ ci,
                                            f32x2* __restrict__ macc) {
    float fx = px*ci[0] + py*ci[3] + pz*ci[6];
    float fy = px*ci[1] + py*ci[4] + pz*ci[7];
    float fz = px*ci[2] + py*ci[5] + pz*ci[8];
    float X[4], Y[4], Z[4];
    axis_w4(fx*(float)NSM, X);
    axis_w4(fy*(float)NSM, Y);
    axis_w4(fz*(float)NSM, Z);
    f32x2 z01; z01.x = Z[0]; z01.y = Z[1];
    f32x2 z23; z23.x = Z[2]; z23.y = Z[3];
    float qX[4];
    #pragma unroll
    for (int x = 0; x < 4; x++) qX[x] = q * X[x];
    #pragma unroll
    for (int x = 0; x < 4; x++) {
        #pragma unroll
        for (int y = 0; y < 4; y++) {
            f32x2 w2 = splat2(qX[x] * Y[y]);
            macc[x*8 + y*2    ] = pkfma(w2, z01, macc[x*8 + y*2    ]);
            macc[x*8 + y*2 + 1] = pkfma(w2, z23, macc[x*8 + y*2 + 1]);
        }
    }
}

__global__ __launch_bounds__(256) void scatter_kernel(
        const float* __restrict__ pos, const float* __restrict__ cell,
        const float* __restrict__ charges, float* __restrict__ partial, int N) {
    __shared__ f32x2 red[128][32];   // 32 KB
    __shared__ f32x2 red2[8][32];    // 2 KB
    float ci[9]; inv3x3(cell, ci);

    f32x2 macc[32];
    #pragma unroll
    for (int c = 0; c < 32; c++) macc[c] = splat2(0.0f);

    const float4* posv = (const float4*)pos;
    const float4* qv   = (const float4*)charges;
    long NB4    = ((long)N + 3) / 4;
    long stride = (long)gridDim.x * blockDim.x;

    #pragma unroll
    for (int pass = 0; pass < 2; pass++) {
        long b = (long)blockIdx.x * blockDim.x + threadIdx.x + pass * stride;
        if (b >= NB4) break;
        long i = b * 4;
        if (i + 3 < N) {
            float4 p0 = posv[3*b], p1 = posv[3*b+1], p2 = posv[3*b+2];
            float4 q4 = qv[b];
            scatter_one(p0.x, p0.y, p0.z, q4.x, ci, macc);
            scatter_one(p0.w, p1.x, p1.y, q4.y, ci, macc);
            scatter_one(p1.z, p1.w, p2.x, q4.z, ci, macc);
            scatter_one(p2.y, p2.z, p2.w, q4.w, ci, macc);
        } else {
            for (long k = i; k < N; k++)
                scatter_one(pos[3*k], pos[3*k+1], pos[3*k+2], charges[k], ci, macc);
        }
    }

    // wave pre-reduce: lane l += lane l^32 -> lower 32 lanes hold pair sums
    #pragma unroll
    for (int c = 0; c < 32; c++) {
        macc[c].x += __shfl_xor(macc[c].x, 32);
        macc[c].y += __shfl_xor(macc[c].y, 32);
    }
    int t = threadIdx.x;
    int row = (t >> 6) * 32 + (t & 31);
    if ((t & 32) == 0) {
        int sw = t & 31;
        #pragma unroll
        for (int c = 0; c < 32; c++) red[row][c ^ sw] = macc[c];
    }
    __syncthreads();
    {
        int p = t & 31, g = t >> 5;
        f32x2 sum = splat2(0.0f);
        #pragma unroll
        for (int i2 = 0; i2 < 16; i2++) {
            int r = g*16 + i2;
            sum += red[r][p ^ (r & 31)];
        }
        red2[g][p] = sum;
    }
    __syncthreads();
    if (t < NCELL) {
        const float* r2 = (const float*)&red2[0][0];
        int pair = t >> 1, comp = t & 1;
        float s = 0.0f;
        #pragma unroll
        for (int gg = 0; gg < 8; gg++) s += r2[(gg*32 + pair)*2 + comp];
        partial[(long)blockIdx.x * NCELL + t] = s;   // plain store, no atomic
    }
}

// ---------- kernel B1: fixed-order tree reduce: nb rows -> 64 rows ----------

__global__ __launch_bounds__(256) void reduce_stage1_kernel(
        const float* __restrict__ partial, int nb, float* __restrict__ partial2) {
    __shared__ float acc[4][64];
    int t = threadIdx.x;
    int c = t & 63, g = t >> 6;
    float s = 0.0f;
    for (int r = blockIdx.x + 64*g; r < nb; r += 256)
        s += partial[(long)r * NCELL + c];
    acc[g][c] = s;
    __syncthreads();
    if (t < 64) {
        float v = ((acc[0][t] + acc[1][t]) + acc[2][t]) + acc[3][t];
        partial2[(long)blockIdx.x * NCELL + t] = v;
    }
}

// ---------- kernel B2: final 64-row reduce + k-space filter ----------
// mesh'[r] = sum_{r'} G[(r-r') mod 4] mesh[r'];  no 1/64 (backward rfft, forward irfft)

__global__ __launch_bounds__(256) void reduce_filter_kernel(
        const float* __restrict__ partial2,
        const float* __restrict__ cell, const float* __restrict__ sigma2p,
        float* __restrict__ mesh_out) {
    __shared__ float4 redA[16][16];
    __shared__ float mm[64];
    __shared__ float gr[64];
    int t = threadIdx.x;

    int c4 = t & 15, g = t >> 4;
    float4 v = make_float4(0.f, 0.f, 0.f, 0.f);
    const float4* p4 = (const float4*)partial2;
    for (int b = g; b < R1_BLOCKS; b += 16) {
        float4 x = p4[b*16 + c4];
        v.x += x.x; v.y += x.y; v.z += x.z; v.w += x.w;
    }
    redA[g][c4] = v;
    __syncthreads();
    if (t < 16) {
        float4 tot = make_float4(0.f, 0.f, 0.f, 0.f);
        #pragma unroll
        for (int gg = 0; gg < 16; gg++) {
            float4 x = redA[gg][t];
            tot.x += x.x; tot.y += x.y; tot.z += x.z; tot.w += x.w;
        }
        ((float4*)mm)[t] = tot;
    }
    __syncthreads();

    if (t < 64) {
        float ci[9]; inv3x3(cell, ci);
        float s2 = sigma2p[0];
        const float twopi = 6.2831853071795864769f;
        float G0x = twopi*ci[0], G0y = twopi*ci[3], G0z = twopi*ci[6];
        float G1x = twopi*ci[1], G1y = twopi*ci[4], G1z = twopi*ci[7];
        float G2x = twopi*ci[2], G2y = twopi*ci[5], G2z = twopi*ci[8];
        int dx = t >> 4, dy = (t >> 2) & 3, dz = t & 3;
        float acc = 0.0f;
        for (int a = 0; a < 4; a++) {
            float fa = (a < 2) ? (float)a : (float)(a - 4);
            for (int b = 0; b < 4; b++) {
                float fb = (b < 2) ? (float)b : (float)(b - 4);
                for (int c = 0; c < 4; c++) {
                    if ((a | b | c) == 0) continue;
                    float fc = (c < 2) ? (float)c : (float)(c - 4);
                    float kx = fa*G0x + fb*G1x + fc*G2x;
                    float ky = fa*G0y + fb*G1y + fc*G2y;
                    float kz = fa*G0z + fb*G1z + fc*G2z;
                    float k2 = kx*kx + ky*ky + kz*kz;
                    float K  = expf(-k2 * s2 * 0.5f) / k2;
                    int ph = (a*dx + b*dy + c*dz) & 3;
                    float cs = (ph == 0) ? 1.0f : ((ph == 2) ? -1.0f : 0.0f);
                    acc += K * cs;
                }
            }
        }
        gr[t] = acc;
    }
    __syncthreads();
    if (t < 64) {
        int dx = t >> 4, dy = (t >> 2) & 3, dz = t & 3;
        float o = 0.0f;
        for (int s = 0; s < 64; s++) {
            int sx = s >> 4, sy = (s >> 2) & 3, sz = s & 3;
            int d = ((dx - sx) & 3)*16 + ((dy - sy) & 3)*4 + ((dz - sz) & 3);
            o += gr[d] * mm[s];
        }
        mesh_out[t] = o;
    }
}

// ---------- kernel C: gather (dense, uniform global s_load mesh), 8 particles/thread ----------

__device__ __forceinline__ float pot_one(float px, float py, float pz,
                                         const float* __restrict__ ci,
                                         const float* __restrict__ mf) {
    float fx = px*ci[0] + py*ci[3] + pz*ci[6];
    float fy = px*ci[1] + py*ci[4] + pz*ci[7];
    float fz = px*ci[2] + py*ci[5] + pz*ci[8];
    float X[4], Y[4], Z[4];
    axis_w4(fx*(float)NSM, X);
    axis_w4(fy*(float)NSM, Y);
    axis_w4(fz*(float)NSM, Z);
    f32x2 a01 = splat2(0.0f), a23 = splat2(0.0f);
    #pragma unroll
    for (int x = 0; x < 4; x++) {
        #pragma unroll
        for (int y = 0; y < 4; y++) {
            f32x2 w2 = splat2(X[x] * Y[y]);
            f32x2 m01, m23;
            m01.x = mf[x*16 + y*4 + 0]; m01.y = mf[x*16 + y*4 + 1];
            m23.x = mf[x*16 + y*4 + 2]; m23.y = mf[x*16 + y*4 + 3];
            a01 = pkfma(w2, m01, a01);
            a23 = pkfma(w2, m23, a23);
        }
    }
    return a01.x*Z[0] + a01.y*Z[1] + a23.x*Z[2] + a23.y*Z[3];
}

__global__ __launch_bounds__(256, 4) void gather_mlp_kernel(
        const float* __restrict__ pos, const float* __restrict__ cell,
        const float* __restrict__ charges,
        const float* __restrict__ W1, const float* __restrict__ b1,
        const float* __restrict__ W2, const float* __restrict__ b2,
        const float* __restrict__ W3, const float* __restrict__ b3,
        const float* __restrict__ meshf, float* __restrict__ bsum, int N) {
    __shared__ float wavesum[4];
    int t = threadIdx.x;
    float ci[9]; inv3x3(cell, ci);

    const float4* posv = (const float4*)pos;
    long NB4    = ((long)N + 3) / 4;
    long stride = (long)gridDim.x * blockDim.x;
    float ysum = 0.0f;

    #pragma unroll
    for (int pass = 0; pass < 2; pass++) {
        long b = (long)blockIdx.x * blockDim.x + threadIdx.x + pass * stride;
        if (b >= NB4) break;
        long i0 = b * 4;
        if (i0 + 3 < N) {
            float4 p0 = posv[3*b], p1 = posv[3*b+1], p2 = posv[3*b+2];
            float4 q4 = ((const float4*)charges)[b];

            float pt0 = pot_one(p0.x, p0.y, p0.z, ci, meshf);
            float pt1 = pot_one(p0.w, p1.x, p1.y, ci, meshf);
            float pt2 = pot_one(p1.z, p1.w, p2.x, ci, meshf);
            float pt3 = pot_one(p2.y, p2.z, p2.w, ci, meshf);

            f32x2 q01; q01.x = q4.x; q01.y = q4.y;
            f32x2 q23; q23.x = q4.z; q23.y = q4.w;
            f32x2 pA;  pA.x = pt0;  pA.y = pt1;
            f32x2 pB;  pB.x = pt2;  pB.y = pt3;

            // weights read raw from global (uniform -> s_load operands)
            f32x2 h1a[10], h1b[10];
            #pragma unroll
            for (int j = 0; j < 10; j++) {
                f32x2 ta = pkfma(pA, splat2(W1[10 + j]), splat2(b1[j]));
                ta = pkfma(q01, splat2(W1[j]), ta);
                h1a[j] = tanh2v(ta);
                f32x2 tb = pkfma(pB, splat2(W1[10 + j]), splat2(b1[j]));
                tb = pkfma(q23, splat2(W1[j]), tb);
                h1b[j] = tanh2v(tb);
            }
            f32x2 h2a[10], h2b[10];
            #pragma unroll
            for (int j = 0; j < 10; j++) {
                f32x2 aa = splat2(b2[j]), ab = splat2(b2[j]);
                #pragma unroll
                for (int i = 0; i < 10; i++) {
                    f32x2 w = splat2(W2[10*i + j]);
                    aa = pkfma(h1a[i], w, aa);
                    ab = pkfma(h1b[i], w, ab);
                }
                h2a[j] = tanh2v(aa);
                h2b[j] = tanh2v(ab);
            }
            f32x2 ya = splat2(b3[0]), yb = splat2(b3[0]);
            #pragma unroll
            for (int j = 0; j < 10; j++) {
                f32x2 w = splat2(W3[j]);
                ya = pkfma(h2a[j], w, ya);
                yb = pkfma(h2b[j], w, yb);
            }
            ysum += ya.x + ya.y + yb.x + yb.y;
        } else {
            for (long k = i0; k < N; k++) {
                float pt = pot_one(pos[3*k], pos[3*k+1], pos[3*k+2], ci, meshf);
                float q  = charges[k];
                float h1[10], h2[10];
                #pragma unroll
                for (int j = 0; j < 10; j++)
                    h1[j] = tanh1(fmaf(q, W1[j], fmaf(pt, W1[10 + j], b1[j])));
                #pragma unroll
                for (int j = 0; j < 10; j++) {
                    float a2 = b2[j];
                    #pragma unroll
                    for (int i = 0; i < 10; i++) a2 = fmaf(h1[i], W2[10*i + j], a2);
                    h2[j] = tanh1(a2);
                }
                float y = b3[0];
                #pragma unroll
                for (int j = 0; j < 10; j++) y = fmaf(h2[j], W3[j], y);
                ysum += y;
            }
        }
    }

    ysum += __shfl_down(ysum, 32);
    ysum += __shfl_down(ysum, 16);
    ysum += __shfl_down(ysum, 8);
    ysum += __shfl_down(ysum, 4);
    ysum += __shfl_down(ysum, 2);
    ysum += __shfl_down(ysum, 1);
    int wid  = t >> 6;
    int lane = t & 63;
    if (lane == 0) wavesum[wid] = ysum;
    __syncthreads();
    if (t == 0)
        bsum[blockIdx.x] = wavesum[0] + wavesum[1] + wavesum[2] + wavesum[3];
}

// ---------- kernel D: deterministic final sum ----------

__global__ __launch_bounds__(256) void final_sum_kernel(
        const float* __restrict__ bsum, int nb, float* __restrict__ out) {
    __shared__ float wavesum[4];
    float s = 0.0f;
    for (int i = threadIdx.x; i < nb; i += 256) s += bsum[i];
    s += __shfl_down(s, 32);
    s += __shfl_down(s, 16);
    s += __shfl_down(s, 8);
    s += __shfl_down(s, 4);
    s += __shfl_down(s, 2);
    s += __shfl_down(s, 1);
    int wid  = threadIdx.x >> 6;
    int lane = threadIdx.x & 63;
    if (lane == 0) wavesum[wid] = s;
    __syncthreads();
    if (threadIdx.x == 0)
        out[0] = wavesum[0] + wavesum[1] + wavesum[2] + wavesum[3];
}

// ---------- launch ----------

extern "C" void kernel_launch(void* const* d_in, const int* in_sizes, int n_in,
                              void* d_out, int out_size, void* d_ws, size_t ws_size,
                              hipStream_t stream) {
    const float* pos     = (const float*)d_in[0];
    const float* cell    = (const float*)d_in[1];
    const float* charges = (const float*)d_in[2];
    const float* sigma2  = (const float*)d_in[3];
    const float* W1 = (const float*)d_in[4];
    const float* b1 = (const float*)d_in[5];
    const float* W2 = (const float*)d_in[6];
    const float* b2 = (const float*)d_in[7];
    const float* W3 = (const float*)d_in[8];
    const float* b3 = (const float*)d_in[9];
    int N = in_sizes[2];                         // charges (N,1)

    int sc_blocks = (int)(((long)N + 2047) / 2048);   // 8 particles/thread
    int ga_blocks = (int)(((long)N + 2047) / 2048);   // 8 particles/thread

    // ws layout: partial[sc_blocks*64] | partial2[64*64] | meshf[64] | bsum[ga_blocks]
    float* partial  = (float*)d_ws;
    float* partial2 = partial + (long)sc_blocks * NCELL;
    float* meshf    = partial2 + (long)R1_BLOCKS * NCELL;
    float* bsum     = meshf + NCELL;

    scatter_kernel<<<sc_blocks, 256, 0, stream>>>(pos, cell, charges, partial, N);
    reduce_stage1_kernel<<<R1_BLOCKS, 256, 0, stream>>>(partial, sc_blocks, partial2);
    reduce_filter_kernel<<<1, 256, 0, stream>>>(partial2, cell, sigma2, meshf);
    gather_mlp_kernel<<<ga_blocks, 256, 0, stream>>>(pos, cell, charges,
                                                     W1, b1, W2, b2, W3, b3,
                                                     meshf, bsum, N);
    final_sum_kernel<<<1, 256, 0, stream>>>(bsum, ga_blocks, (float*)d_out);
}